// Round 5
// baseline (353.084 us; speedup 1.0000x reference)
//
#include <hip/hip_runtime.h>
#include <math.h>

#define KEY_DIM   512
#define VALUE_DIM 128
#define CAP       500000
#define NRET      32
#define LN_EPS    1e-5f
#define NORM_EPS  1e-12f
#define NEG_INF   (-3.402823466e38f)
#define IDX_INF   0x7fffffff

#define ROWS_PER_WAVE  128
#define ROWS_PER_BLOCK 512
#define SCAN_BLOCKS    977            // ceil(500000/512); 977*512 = 500224
#define NCAND          (SCAN_BLOCKS * NRET)   // 31264
#define FIN_SLOTS      31             // 31*1024 = 31744 >= 31264

// ---------------- cross-lane primitives ----------------

template<int CTRL>
__device__ inline float dppMovF(float x) {
  return __int_as_float(__builtin_amdgcn_update_dpp(0, __float_as_int(x), CTRL, 0xF, 0xF, true));
}

// sum over the 16-lane DPP row, result in all 16 lanes; pure VALU (no DS)
__device__ inline float rowSum16(float x) {
  x += dppMovF<0xB1>(x);    // quad_perm xor1
  x += dppMovF<0x4E>(x);    // quad_perm xor2
  x += dppMovF<0x124>(x);   // row_ror:4
  x += dppMovF<0x128>(x);   // row_ror:8
  return x;
}

// full 64-lane sum, result in every lane
__device__ inline float waveSumF(float x) {
  x = rowSum16(x);
  x += __int_as_float(__builtin_amdgcn_ds_swizzle(__float_as_int(x), 0x401F)); // xor16
  x += __shfl_xor(x, 32);                                                      // xor32
  return x;
}

template<int D>
__device__ inline int fetchI(int x) {
  if constexpr (D == 1)       return __builtin_amdgcn_update_dpp(0, x, 0xB1, 0xF, 0xF, true);
  else if constexpr (D == 2)  return __builtin_amdgcn_update_dpp(0, x, 0x4E, 0xF, 0xF, true);
  else if constexpr (D == 4)  return __builtin_amdgcn_ds_swizzle(x, 0x101F);  // xor4
  else if constexpr (D == 8)  return __builtin_amdgcn_ds_swizzle(x, 0x201F);  // xor8
  else if constexpr (D == 16) return __builtin_amdgcn_ds_swizzle(x, 0x401F);  // xor16
  else                        return __shfl_xor(x, 32);                       // xor32
}
template<int D>
__device__ inline float fetchF(float x) { return __int_as_float(fetchI<D>(__float_as_int(x))); }

// one butterfly step of argmax by (v desc, gi asc) carrying payload code
template<int D>
__device__ inline void amStep(float& v, int& g, int& c) {
  float ov = fetchF<D>(v); int og = fetchI<D>(g); int oc = fetchI<D>(c);
  if (ov > v || (ov == v && og < g)) { v = ov; g = og; c = oc; }
}
__device__ inline void waveArgMax3(float& v, int& g, int& c) {
  amStep<1>(v, g, c); amStep<2>(v, g, c); amStep<4>(v, g, c);
  amStep<8>(v, g, c); amStep<16>(v, g, c); amStep<32>(v, g, c);
}

// bitonic compare-exchange, partner at lane^D (same register)
template<int D>
__device__ inline void ceStageLane(float& v, int& gi, bool desc, int lane) {
  float ov = fetchF<D>(v); int og = fetchI<D>(gi);
  bool better  = (ov > v) || (ov == v && og < gi);
  bool amLower = (lane & D) == 0;
  bool keepMax = (amLower == desc);
  if (keepMax == better) { v = ov; gi = og; }
}

// bitonic compare-exchange between two registers (A holds the lower element id)
__device__ inline void ceStageReg(float& vA, int& gA, float& vB, int& gB, bool desc) {
  bool better = (vB > vA) || (vB == vA && gB < gA);
  bool sw = (better == desc);
  float tv = sw ? vB : vA; vB = sw ? vA : vB; vA = tv;
  int   tg = sw ? gB : gA; gB = sw ? gA : gB; gA = tg;
}

// ---------------- MLP matvecs ----------------

__global__ __launch_bounds__(256) void matvec1_kernel(
    const float* __restrict__ query, const float* __restrict__ W1,
    const float* __restrict__ b1, float* __restrict__ h)
{
  int tid = threadIdx.x, wid = tid >> 6, lane = tid & 63;
  int row = (blockIdx.x << 2) + wid;
  const float4* q4 = (const float4*)query;
  const float4* wrow = (const float4*)(W1 + (size_t)row * KEY_DIM);
  float4 a0 = wrow[lane],      q0 = q4[lane];
  float4 a1 = wrow[lane + 64], q1 = q4[lane + 64];
  float acc = a0.x*q0.x + a0.y*q0.y + a0.z*q0.z + a0.w*q0.w
            + a1.x*q1.x + a1.y*q1.y + a1.z*q1.z + a1.w*q1.w;
  acc = waveSumF(acc);
  if (lane == 0) {
    float x = acc + b1[row];
    h[row] = x / (1.f + expf(-x));   // silu
  }
}

__global__ __launch_bounds__(256) void matvec2_kernel(
    const float* __restrict__ h, const float* __restrict__ W2,
    const float* __restrict__ b2, float* __restrict__ g)
{
  int tid = threadIdx.x, wid = tid >> 6, lane = tid & 63;
  int row = (blockIdx.x << 2) + wid;
  const float4* h4 = (const float4*)h;
  const float4* wrow = (const float4*)(W2 + (size_t)row * KEY_DIM);
  float4 a0 = wrow[lane],      q0 = h4[lane];
  float4 a1 = wrow[lane + 64], q1 = h4[lane + 64];
  float acc = a0.x*q0.x + a0.y*q0.y + a0.z*q0.z + a0.w*q0.w
            + a1.x*q1.x + a1.y*q1.y + a1.z*q1.z + a1.w*q1.w;
  acc = waveSumF(acc);
  if (lane == 0) g[row] = acc + b2[row];
}

// ---------------- scan: 16-lane-group rows + 2-deep pipeline + sort-128 + block merge ----------------
// 977 blocks x 256 (4 waves); wave owns 128 consecutive rows; 4 rows/step, 32 steps.
// lane (grp=lane>>4, sub=lane&15) reads row (base+grp), bytes sub*16 + k*256 (k=0..7).

__global__ __launch_bounds__(256, 4) void scan_kernel(
    const float* __restrict__ keys, const float* __restrict__ g,
    const float* __restrict__ ln_g, const float* __restrict__ ln_b,
    float* __restrict__ cand_val, int* __restrict__ cand_idx)
{
  __shared__ float qs[512];
  __shared__ float lv[128];
  __shared__ int   li[128];
  const int tid = threadIdx.x, wid = tid >> 6, lane = tid & 63;
  const int sub = lane & 15, grp = lane >> 4;

  // ---- wave 0: LayerNorm + L2-normalize g[512] -> qs (block-shared) ----
  if (wid == 0) {
    const float4* g4 = (const float4*)g;
    float4 x0 = g4[lane], x1 = g4[lane + 64];
    float psum = x0.x + x0.y + x0.z + x0.w + x1.x + x1.y + x1.z + x1.w;
    float mu = waveSumF(psum) * (1.f / 512.f);
    float4 d0, d1;
    d0.x = x0.x - mu; d0.y = x0.y - mu; d0.z = x0.z - mu; d0.w = x0.w - mu;
    d1.x = x1.x - mu; d1.y = x1.y - mu; d1.z = x1.z - mu; d1.w = x1.w - mu;
    float pvar = d0.x*d0.x + d0.y*d0.y + d0.z*d0.z + d0.w*d0.w
               + d1.x*d1.x + d1.y*d1.y + d1.z*d1.z + d1.w*d1.w;
    float var  = waveSumF(pvar) * (1.f / 512.f);
    float rstd = 1.f / sqrtf(var + LN_EPS);
    const float4* lg4 = (const float4*)ln_g;
    const float4* lb4 = (const float4*)ln_b;
    float4 a0 = lg4[lane], a1 = lg4[lane + 64];
    float4 b0 = lb4[lane], b1 = lb4[lane + 64];
    float4 y0, y1;
    y0.x = d0.x*rstd*a0.x + b0.x; y0.y = d0.y*rstd*a0.y + b0.y;
    y0.z = d0.z*rstd*a0.z + b0.z; y0.w = d0.w*rstd*a0.w + b0.w;
    y1.x = d1.x*rstd*a1.x + b1.x; y1.y = d1.y*rstd*a1.y + b1.y;
    y1.z = d1.z*rstd*a1.z + b1.z; y1.w = d1.w*rstd*a1.w + b1.w;
    float pn  = y0.x*y0.x + y0.y*y0.y + y0.z*y0.z + y0.w*y0.w
              + y1.x*y1.x + y1.y*y1.y + y1.z*y1.z + y1.w*y1.w;
    float nsq = waveSumF(pn);
    float nf  = 1.f / fmaxf(sqrtf(nsq), NORM_EPS);
    float4 q0, q1;
    q0.x = y0.x*nf; q0.y = y0.y*nf; q0.z = y0.z*nf; q0.w = y0.w*nf;
    q1.x = y1.x*nf; q1.y = y1.y*nf; q1.z = y1.z*nf; q1.w = y1.w*nf;
    ((float4*)qs)[lane]      = q0;
    ((float4*)qs)[lane + 64] = q1;
  }
  __syncthreads();

  // lane's q fragment: qf[k] = floats [k*64 + sub*4 .. +4)
  float4 qf[8];
  {
    const float4* qs4 = (const float4*)qs;
    #pragma unroll
    for (int k = 0; k < 8; ++k) qf[k] = qs4[(k << 4) + sub];
  }

  const int wrow0 = blockIdx.x * ROWS_PER_BLOCK + wid * ROWS_PER_WAVE;
  const char* kbase = (const char*)keys + (size_t)sub * 16;

  float4 buf[2][8];
  float sv0 = NEG_INF, sv1 = NEG_INF;

  // prologue: prefetch step 0
  {
    int r = min(wrow0 + grp, CAP - 1);
    const char* p = kbase + (size_t)r * 2048;
    #pragma unroll
    for (int k = 0; k < 8; ++k) buf[0][k] = *(const float4*)(p + (k << 8));
  }

  #pragma unroll 1
  for (int jo = 0; jo < 4; ++jo) {
    #pragma unroll
    for (int ju = 0; ju < 8; ++ju) {
      const int j = (jo << 3) + ju;           // uniform
      const int cur = ju & 1, nxt = cur ^ 1;  // static indices
      // prefetch step j+1 (row-clamped; j=31 overrun hits a cached row)
      {
        int rn = min(wrow0 + ((j + 1) << 2) + grp, CAP - 1);
        const char* p = kbase + (size_t)rn * 2048;
        #pragma unroll
        for (int k = 0; k < 8; ++k) buf[nxt][k] = *(const float4*)(p + (k << 8));
      }
      // compute step j from buf[cur]
      float dot = 0.f, ss = 0.f;
      #pragma unroll
      for (int k = 0; k < 8; ++k) {
        float4 a = buf[cur][k];
        dot += a.x*qf[k].x + a.y*qf[k].y + a.z*qf[k].z + a.w*qf[k].w;
        ss  += a.x*a.x + a.y*a.y + a.z*a.z + a.w*a.w;
      }
      dot = rowSum16(dot);
      ss  = rowSum16(ss);
      float sim = dot / fmaxf(sqrtf(ss), NORM_EPS);
      int r = wrow0 + (j << 2) + grp;
      sim = (r < CAP) ? sim : NEG_INF;
      bool cap = (sub == (j & 15));
      if (j < 16) { if (cap) sv0 = sim; }   // uniform branch
      else        { if (cap) sv1 = sim; }
    }
  }

  // captured rows: sv0 -> wrow0 + sub*4 + grp ; sv1 -> +64
  int sg0 = wrow0 + (sub << 2) + grp;
  int sg1 = sg0 + 64;

  // ---- bitonic sort of 128 (element e = reg*64 + lane), desc by (v, gi asc) ----
  #define LST2(D, A0, A1) \
    ceStageLane<D>(sv0, sg0, A0, lane); \
    ceStageLane<D>(sv1, sg1, A1, lane);
  { bool dm = (lane & 2) == 0;  LST2(1, dm,dm) }
  { bool dm = (lane & 4) == 0;  LST2(2, dm,dm)  LST2(1, dm,dm) }
  { bool dm = (lane & 8) == 0;  LST2(4, dm,dm)  LST2(2, dm,dm)  LST2(1, dm,dm) }
  { bool dm = (lane & 16) == 0; LST2(8, dm,dm)  LST2(4, dm,dm)  LST2(2, dm,dm)  LST2(1, dm,dm) }
  { bool dm = (lane & 32) == 0; LST2(16, dm,dm) LST2(8, dm,dm)  LST2(4, dm,dm)
                                LST2(2, dm,dm)  LST2(1, dm,dm) }
  // m=64: desc(e) = ((e&64)==0) -> reg0 true, reg1 false
  LST2(32, true,false) LST2(16, true,false) LST2(8, true,false)
  LST2(4,  true,false) LST2(2,  true,false) LST2(1, true,false)
  // m=128 (final, all desc): d=64 cross-reg, then lane stages
  ceStageReg(sv0, sg0, sv1, sg1, true);
  LST2(32, true,true) LST2(16, true,true) LST2(8, true,true)
  LST2(4,  true,true) LST2(2,  true,true) LST2(1, true,true)
  #undef LST2

  // ---- block merge: 4 waves x top-32 -> block top-32 ----
  if (lane < NRET) { lv[(wid << 5) + lane] = sv0; li[(wid << 5) + lane] = sg0; }
  __syncthreads();
  if (wid == 0) {
    float c0 = lv[lane], c1 = lv[64 + lane];
    int   h0 = li[lane], h1 = li[64 + lane];
    for (int it = 0; it < NRET; ++it) {
      bool p1 = (c1 > c0) || (c1 == c0 && h1 < h0);
      float bv = p1 ? c1 : c0; int bg = p1 ? h1 : h0;
      int code = (lane << 1) | (p1 ? 1 : 0);
      waveArgMax3(bv, bg, code);
      if (lane == (code >> 1)) { if (code & 1) c1 = NEG_INF; else c0 = NEG_INF; }
      if (lane == 0) {
        cand_val[(blockIdx.x << 5) + it] = bv;
        cand_idx[(blockIdx.x << 5) + it] = bg;
      }
    }
  }
}

// ---------------- final: 31264 -> top-32, softmax, weighted gather ----------------
// 1 block x 1024 (16 waves); per-wave extraction, then wave 0 over 512, then output

__global__ __launch_bounds__(1024) void final_kernel(
    const float* __restrict__ cv, const int* __restrict__ ci, int n,
    const float* __restrict__ values, float* __restrict__ out)
{
  __shared__ float wv[512];
  __shared__ int   wgi[512];
  __shared__ float selv[NRET];
  __shared__ int   seli[NRET];
  __shared__ float attn[NRET];
  int tid = threadIdx.x, wid = tid >> 6, lane = tid & 63;

  float vs[FIN_SLOTS]; int gs[FIN_SLOTS];
  #pragma unroll
  for (int k = 0; k < FIN_SLOTS; ++k) {
    int idx = (k << 10) + tid;
    bool ok = idx < n;
    vs[k] = ok ? cv[idx] : NEG_INF;
    gs[k] = ok ? ci[idx] : IDX_INF;
  }
  // per-wave top-32 extraction
  for (int it = 0; it < NRET; ++it) {
    float bv = vs[0]; int bg = gs[0]; int bs = 0;
    #pragma unroll
    for (int k = 1; k < FIN_SLOTS; ++k)
      if (vs[k] > bv || (vs[k] == bv && gs[k] < bg)) { bv = vs[k]; bg = gs[k]; bs = k; }
    int code = (lane << 5) | bs;
    waveArgMax3(bv, bg, code);
    if (lane == (code >> 5)) {
      int s = code & 31;
      #pragma unroll
      for (int k = 0; k < FIN_SLOTS; ++k) if (k == s) vs[k] = NEG_INF;
    }
    if (lane == 0) { wv[(wid << 5) + it] = bv; wgi[(wid << 5) + it] = bg; }
  }
  __syncthreads();
  // wave 0: 512 -> 32 (8 slots/lane)
  if (wid == 0) {
    float fs[8]; int fg[8];
    #pragma unroll
    for (int k = 0; k < 8; ++k) { fs[k] = wv[(k << 6) + lane]; fg[k] = wgi[(k << 6) + lane]; }
    for (int it = 0; it < NRET; ++it) {
      float bv = fs[0]; int bg = fg[0]; int bs = 0;
      #pragma unroll
      for (int k = 1; k < 8; ++k)
        if (fs[k] > bv || (fs[k] == bv && fg[k] < bg)) { bv = fs[k]; bg = fg[k]; bs = k; }
      int code = (lane << 3) | bs;
      waveArgMax3(bv, bg, code);
      if (lane == (code >> 3)) {
        int s = code & 7;
        #pragma unroll
        for (int k = 0; k < 8; ++k) if (k == s) fs[k] = NEG_INF;
      }
      if (lane == 0) { selv[it] = bv; seli[it] = bg; }
    }
  }
  __syncthreads();
  if (tid < NRET) {
    float e = expf(selv[tid] - selv[0]);   // selv[0] is the max
    float s = e;
    #pragma unroll
    for (int off = 16; off; off >>= 1) s += __shfl_xor(s, off);
    attn[tid] = e / s;
  }
  __syncthreads();
  if (tid < VALUE_DIM) {
    float acc = 0.f;
    #pragma unroll
    for (int k = 0; k < NRET; ++k)
      acc += attn[k] * values[(size_t)seli[k] * VALUE_DIM + tid];
    out[tid] = acc;
  }
}

// ---------------- launch ----------------

extern "C" void kernel_launch(void* const* d_in, const int* in_sizes, int n_in,
                              void* d_out, int out_size, void* d_ws, size_t ws_size,
                              hipStream_t stream) {
  const float* query  = (const float*)d_in[0];
  const float* W1     = (const float*)d_in[1];
  const float* b1     = (const float*)d_in[2];
  const float* W2     = (const float*)d_in[3];
  const float* b2     = (const float*)d_in[4];
  const float* ln_g   = (const float*)d_in[5];
  const float* ln_b   = (const float*)d_in[6];
  const float* keys   = (const float*)d_in[7];
  const float* values = (const float*)d_in[8];
  float* out = (float*)d_out;

  float* wsf = (float*)d_ws;
  float* h        = wsf;                               // 512
  float* g        = wsf + 512;                         // 512
  float* cand_val = wsf + 1024;                        // NCAND
  int*   cand_idx = (int*)(wsf + 1024 + NCAND);        // NCAND

  hipLaunchKernelGGL(matvec1_kernel, dim3(128), dim3(256), 0, stream, query, W1, b1, h);
  hipLaunchKernelGGL(matvec2_kernel, dim3(128), dim3(256), 0, stream, h, W2, b2, g);
  hipLaunchKernelGGL(scan_kernel, dim3(SCAN_BLOCKS), dim3(256), 0, stream,
                     keys, g, ln_g, ln_b, cand_val, cand_idx);
  hipLaunchKernelGGL(final_kernel, dim3(1), dim3(1024), 0, stream,
                     cand_val, cand_idx, NCAND, values, out);
}

// Round 7
// 315.564 us; speedup vs baseline: 1.1189x; 1.1189x over previous
//
#include <hip/hip_runtime.h>
#include <math.h>

#define KEY_DIM   512
#define VALUE_DIM 128
#define CAP       500000
#define NRET      32
#define LN_EPS    1e-5f
#define NORM_EPS  1e-12f
#define NEG_INF   (-3.402823466e38f)
#define IDX_INF   0x7fffffff

#define ROWS_PER_WAVE  128
#define ROWS_PER_BLOCK 512
#define SCAN_BLOCKS    977            // ceil(500000/512); 977*512 = 500224
#define NCAND          (SCAN_BLOCKS * NRET)   // 31264
#define FIN_SLOTS      31             // 31*1024 = 31744 >= 31264

typedef float floatx4 __attribute__((ext_vector_type(4)));

// ---------------- cross-lane primitives ----------------

template<int CTRL>
__device__ inline float dppMovF(float x) {
  return __int_as_float(__builtin_amdgcn_update_dpp(0, __float_as_int(x), CTRL, 0xF, 0xF, true));
}

// sum over the 16-lane DPP row, result in all 16 lanes; pure VALU (no DS)
__device__ inline float rowSum16(float x) {
  x += dppMovF<0xB1>(x);    // quad_perm xor1
  x += dppMovF<0x4E>(x);    // quad_perm xor2
  x += dppMovF<0x124>(x);   // row_ror:4
  x += dppMovF<0x128>(x);   // row_ror:8
  return x;
}

// full 64-lane sum, result in every lane
__device__ inline float waveSumF(float x) {
  x = rowSum16(x);
  x += __int_as_float(__builtin_amdgcn_ds_swizzle(__float_as_int(x), 0x401F)); // xor16
  x += __shfl_xor(x, 32);                                                      // xor32
  return x;
}

template<int D>
__device__ inline int fetchI(int x) {
  if constexpr (D == 1)       return __builtin_amdgcn_update_dpp(0, x, 0xB1, 0xF, 0xF, true);
  else if constexpr (D == 2)  return __builtin_amdgcn_update_dpp(0, x, 0x4E, 0xF, 0xF, true);
  else if constexpr (D == 4)  return __builtin_amdgcn_ds_swizzle(x, 0x101F);  // xor4
  else if constexpr (D == 8)  return __builtin_amdgcn_ds_swizzle(x, 0x201F);  // xor8
  else if constexpr (D == 16) return __builtin_amdgcn_ds_swizzle(x, 0x401F);  // xor16
  else                        return __shfl_xor(x, 32);                       // xor32
}
template<int D>
__device__ inline float fetchF(float x) { return __int_as_float(fetchI<D>(__float_as_int(x))); }

// one butterfly step of argmax by (v desc, gi asc) carrying payload code
template<int D>
__device__ inline void amStep(float& v, int& g, int& c) {
  float ov = fetchF<D>(v); int og = fetchI<D>(g); int oc = fetchI<D>(c);
  if (ov > v || (ov == v && og < g)) { v = ov; g = og; c = oc; }
}
__device__ inline void waveArgMax3(float& v, int& g, int& c) {
  amStep<1>(v, g, c); amStep<2>(v, g, c); amStep<4>(v, g, c);
  amStep<8>(v, g, c); amStep<16>(v, g, c); amStep<32>(v, g, c);
}

// bitonic compare-exchange, partner at lane^D (same register)
template<int D>
__device__ inline void ceStageLane(float& v, int& gi, bool desc, int lane) {
  float ov = fetchF<D>(v); int og = fetchI<D>(gi);
  bool better  = (ov > v) || (ov == v && og < gi);
  bool amLower = (lane & D) == 0;
  bool keepMax = (amLower == desc);
  if (keepMax == better) { v = ov; gi = og; }
}

// bitonic compare-exchange between two registers (A holds the lower element id)
__device__ inline void ceStageReg(float& vA, int& gA, float& vB, int& gB, bool desc) {
  bool better = (vB > vA) || (vB == vA && gB < gA);
  bool sw = (better == desc);
  float tv = sw ? vB : vA; vB = sw ? vA : vB; vA = tv;
  int   tg = sw ? gB : gA; gB = sw ? gA : gB; gA = tg;
}

// non-temporal 16B load (nt bit -> bypass cache fill for single-use stream)
__device__ inline float4 ntLoad4(const float* p) {
  floatx4 r = __builtin_nontemporal_load((const floatx4*)p);
  return make_float4(r.x, r.y, r.z, r.w);
}

// ---------------- MLP matvecs ----------------

__global__ __launch_bounds__(256) void matvec1_kernel(
    const float* __restrict__ query, const float* __restrict__ W1,
    const float* __restrict__ b1, float* __restrict__ h)
{
  int tid = threadIdx.x, wid = tid >> 6, lane = tid & 63;
  int row = (blockIdx.x << 2) + wid;
  const float4* q4 = (const float4*)query;
  const float4* wrow = (const float4*)(W1 + (size_t)row * KEY_DIM);
  float4 a0 = wrow[lane],      q0 = q4[lane];
  float4 a1 = wrow[lane + 64], q1 = q4[lane + 64];
  float acc = a0.x*q0.x + a0.y*q0.y + a0.z*q0.z + a0.w*q0.w
            + a1.x*q1.x + a1.y*q1.y + a1.z*q1.z + a1.w*q1.w;
  acc = waveSumF(acc);
  if (lane == 0) {
    float x = acc + b1[row];
    h[row] = x / (1.f + expf(-x));   // silu
  }
}

__global__ __launch_bounds__(256) void matvec2_kernel(
    const float* __restrict__ h, const float* __restrict__ W2,
    const float* __restrict__ b2, float* __restrict__ g)
{
  int tid = threadIdx.x, wid = tid >> 6, lane = tid & 63;
  int row = (blockIdx.x << 2) + wid;
  const float4* h4 = (const float4*)h;
  const float4* wrow = (const float4*)(W2 + (size_t)row * KEY_DIM);
  float4 a0 = wrow[lane],      q0 = h4[lane];
  float4 a1 = wrow[lane + 64], q1 = h4[lane + 64];
  float acc = a0.x*q0.x + a0.y*q0.y + a0.z*q0.z + a0.w*q0.w
            + a1.x*q1.x + a1.y*q1.y + a1.z*q1.z + a1.w*q1.w;
  acc = waveSumF(acc);
  if (lane == 0) g[row] = acc + b2[row];
}

// ---------------- scan: 64-lane rows, batch-of-8, NT loads, sort-128, block merge ----------------
// 977 blocks x 256 (4 waves); wave owns 128 consecutive rows; 16 batches x 8 rows.
// Per row: lanes read float4 slots r*128+lane and r*128+64+lane (2 x 1KB coalesced).

__global__ __launch_bounds__(256, 4) void scan_kernel(
    const float* __restrict__ keys, const float* __restrict__ g,
    const float* __restrict__ ln_g, const float* __restrict__ ln_b,
    float* __restrict__ cand_val, int* __restrict__ cand_idx)
{
  __shared__ float qs[512];
  __shared__ float lv[128];
  __shared__ int   li[128];
  const int tid = threadIdx.x, wid = tid >> 6, lane = tid & 63;

  // ---- wave 0: LayerNorm + L2-normalize g[512] -> qs (block-shared) ----
  if (wid == 0) {
    const float4* g4 = (const float4*)g;
    float4 x0 = g4[lane], x1 = g4[lane + 64];
    float psum = x0.x + x0.y + x0.z + x0.w + x1.x + x1.y + x1.z + x1.w;
    float mu = waveSumF(psum) * (1.f / 512.f);
    float4 d0, d1;
    d0.x = x0.x - mu; d0.y = x0.y - mu; d0.z = x0.z - mu; d0.w = x0.w - mu;
    d1.x = x1.x - mu; d1.y = x1.y - mu; d1.z = x1.z - mu; d1.w = x1.w - mu;
    float pvar = d0.x*d0.x + d0.y*d0.y + d0.z*d0.z + d0.w*d0.w
               + d1.x*d1.x + d1.y*d1.y + d1.z*d1.z + d1.w*d1.w;
    float var  = waveSumF(pvar) * (1.f / 512.f);
    float rstd = 1.f / sqrtf(var + LN_EPS);
    const float4* lg4 = (const float4*)ln_g;
    const float4* lb4 = (const float4*)ln_b;
    float4 a0 = lg4[lane], a1 = lg4[lane + 64];
    float4 b0 = lb4[lane], b1 = lb4[lane + 64];
    float4 y0, y1;
    y0.x = d0.x*rstd*a0.x + b0.x; y0.y = d0.y*rstd*a0.y + b0.y;
    y0.z = d0.z*rstd*a0.z + b0.z; y0.w = d0.w*rstd*a0.w + b0.w;
    y1.x = d1.x*rstd*a1.x + b1.x; y1.y = d1.y*rstd*a1.y + b1.y;
    y1.z = d1.z*rstd*a1.z + b1.z; y1.w = d1.w*rstd*a1.w + b1.w;
    float pn  = y0.x*y0.x + y0.y*y0.y + y0.z*y0.z + y0.w*y0.w
              + y1.x*y1.x + y1.y*y1.y + y1.z*y1.z + y1.w*y1.w;
    float nsq = waveSumF(pn);
    float nf  = 1.f / fmaxf(sqrtf(nsq), NORM_EPS);
    float4 q0, q1;
    q0.x = y0.x*nf; q0.y = y0.y*nf; q0.z = y0.z*nf; q0.w = y0.w*nf;
    q1.x = y1.x*nf; q1.y = y1.y*nf; q1.z = y1.z*nf; q1.w = y1.w*nf;
    ((float4*)qs)[lane]      = q0;
    ((float4*)qs)[lane + 64] = q1;
  }
  __syncthreads();

  const float4 q0 = ((const float4*)qs)[lane];
  const float4 q1 = ((const float4*)qs)[lane + 64];
  const int wrow0 = blockIdx.x * ROWS_PER_BLOCK + wid * ROWS_PER_WAVE;

  float sv0 = NEG_INF, sv1 = NEG_INF;

  #pragma unroll 1
  for (int jb = 0; jb < 16; ++jb) {
    const int r0 = wrow0 + (jb << 3);
    float4 A[8], B[8];
    #pragma unroll
    for (int i = 0; i < 8; ++i) {
      int rr = min(r0 + i, CAP - 1);
      const float* rp = keys + (size_t)rr * 512;
      A[i] = ntLoad4(rp + (lane << 2));
      B[i] = ntLoad4(rp + 256 + (lane << 2));
    }
    float dt[8], sq[8];
    #pragma unroll
    for (int i = 0; i < 8; ++i) {
      dt[i] = A[i].x*q0.x + A[i].y*q0.y + A[i].z*q0.z + A[i].w*q0.w
            + B[i].x*q1.x + B[i].y*q1.y + B[i].z*q1.z + B[i].w*q1.w;
      sq[i] = A[i].x*A[i].x + A[i].y*A[i].y + A[i].z*A[i].z + A[i].w*A[i].w
            + B[i].x*B[i].x + B[i].y*B[i].y + B[i].z*B[i].z + B[i].w*B[i].w;
    }
    #pragma unroll
    for (int i = 0; i < 8; ++i) { dt[i] = waveSumF(dt[i]); sq[i] = waveSumF(sq[i]); }
    #pragma unroll
    for (int i = 0; i < 8; ++i) {
      float sim = dt[i] / fmaxf(sqrtf(sq[i]), NORM_EPS);
      bool ok = (r0 + i) < CAP;
      sim = ok ? sim : NEG_INF;
      int j = (jb << 3) + i;                 // 0..127, uniform
      bool cap = (lane == (j & 63));
      if (j < 64) { if (cap) sv0 = sim; }    // uniform branch
      else        { if (cap) sv1 = sim; }
    }
  }

  int sg0 = wrow0 + lane;
  int sg1 = wrow0 + 64 + lane;

  // ---- bitonic sort of 128 (element e = reg*64 + lane), desc by (v, gi asc) ----
  #define LST2(D, A0, A1) \
    ceStageLane<D>(sv0, sg0, A0, lane); \
    ceStageLane<D>(sv1, sg1, A1, lane);
  { bool dm = (lane & 2) == 0;  LST2(1, dm,dm) }
  { bool dm = (lane & 4) == 0;  LST2(2, dm,dm)  LST2(1, dm,dm) }
  { bool dm = (lane & 8) == 0;  LST2(4, dm,dm)  LST2(2, dm,dm)  LST2(1, dm,dm) }
  { bool dm = (lane & 16) == 0; LST2(8, dm,dm)  LST2(4, dm,dm)  LST2(2, dm,dm)  LST2(1, dm,dm) }
  { bool dm = (lane & 32) == 0; LST2(16, dm,dm) LST2(8, dm,dm)  LST2(4, dm,dm)
                                LST2(2, dm,dm)  LST2(1, dm,dm) }
  // m=64: desc(e) = ((e&64)==0) -> reg0 true, reg1 false
  LST2(32, true,false) LST2(16, true,false) LST2(8, true,false)
  LST2(4,  true,false) LST2(2,  true,false) LST2(1, true,false)
  // m=128 (final, all desc): d=64 cross-reg, then lane stages
  ceStageReg(sv0, sg0, sv1, sg1, true);
  LST2(32, true,true) LST2(16, true,true) LST2(8, true,true)
  LST2(4,  true,true) LST2(2,  true,true) LST2(1, true,true)
  #undef LST2

  // ---- block merge: 4 waves x top-32 -> block top-32 ----
  if (lane < NRET) { lv[(wid << 5) + lane] = sv0; li[(wid << 5) + lane] = sg0; }
  __syncthreads();
  if (wid == 0) {
    float c0 = lv[lane], c1 = lv[64 + lane];
    int   h0 = li[lane], h1 = li[64 + lane];
    for (int it = 0; it < NRET; ++it) {
      bool p1 = (c1 > c0) || (c1 == c0 && h1 < h0);
      float bv = p1 ? c1 : c0; int bg = p1 ? h1 : h0;
      int code = (lane << 1) | (p1 ? 1 : 0);
      waveArgMax3(bv, bg, code);
      if (lane == (code >> 1)) { if (code & 1) c1 = NEG_INF; else c0 = NEG_INF; }
      if (lane == 0) {
        cand_val[(blockIdx.x << 5) + it] = bv;
        cand_idx[(blockIdx.x << 5) + it] = bg;
      }
    }
  }
}

// ---------------- final: 31264 -> top-32, softmax, weighted gather ----------------
// 1 block x 1024 (16 waves); per-wave extraction, then wave 0 over 512, then output

__global__ __launch_bounds__(1024) void final_kernel(
    const float* __restrict__ cv, const int* __restrict__ ci, int n,
    const float* __restrict__ values, float* __restrict__ out)
{
  __shared__ float wv[512];
  __shared__ int   wgi[512];
  __shared__ float selv[NRET];
  __shared__ int   seli[NRET];
  __shared__ float attn[NRET];
  int tid = threadIdx.x, wid = tid >> 6, lane = tid & 63;

  float vs[FIN_SLOTS]; int gs[FIN_SLOTS];
  #pragma unroll
  for (int k = 0; k < FIN_SLOTS; ++k) {
    int idx = (k << 10) + tid;
    bool ok = idx < n;
    vs[k] = ok ? cv[idx] : NEG_INF;
    gs[k] = ok ? ci[idx] : IDX_INF;
  }
  // per-wave top-32 extraction
  for (int it = 0; it < NRET; ++it) {
    float bv = vs[0]; int bg = gs[0]; int bs = 0;
    #pragma unroll
    for (int k = 1; k < FIN_SLOTS; ++k)
      if (vs[k] > bv || (vs[k] == bv && gs[k] < bg)) { bv = vs[k]; bg = gs[k]; bs = k; }
    int code = (lane << 5) | bs;
    waveArgMax3(bv, bg, code);
    if (lane == (code >> 5)) {
      int s = code & 31;
      #pragma unroll
      for (int k = 0; k < FIN_SLOTS; ++k) if (k == s) vs[k] = NEG_INF;
    }
    if (lane == 0) { wv[(wid << 5) + it] = bv; wgi[(wid << 5) + it] = bg; }
  }
  __syncthreads();
  // wave 0: 512 -> 32 (8 slots/lane)
  if (wid == 0) {
    float fs[8]; int fg[8];
    #pragma unroll
    for (int k = 0; k < 8; ++k) { fs[k] = wv[(k << 6) + lane]; fg[k] = wgi[(k << 6) + lane]; }
    for (int it = 0; it < NRET; ++it) {
      float bv = fs[0]; int bg = fg[0]; int bs = 0;
      #pragma unroll
      for (int k = 1; k < 8; ++k)
        if (fs[k] > bv || (fs[k] == bv && fg[k] < bg)) { bv = fs[k]; bg = fg[k]; bs = k; }
      int code = (lane << 3) | bs;
      waveArgMax3(bv, bg, code);
      if (lane == (code >> 3)) {
        int s = code & 7;
        #pragma unroll
        for (int k = 0; k < 8; ++k) if (k == s) fs[k] = NEG_INF;
      }
      if (lane == 0) { selv[it] = bv; seli[it] = bg; }
    }
  }
  __syncthreads();
  if (tid < NRET) {
    float e = expf(selv[tid] - selv[0]);   // selv[0] is the max
    float s = e;
    #pragma unroll
    for (int off = 16; off; off >>= 1) s += __shfl_xor(s, off);
    attn[tid] = e / s;
  }
  __syncthreads();
  if (tid < VALUE_DIM) {
    float acc = 0.f;
    #pragma unroll
    for (int k = 0; k < NRET; ++k)
      acc += attn[k] * values[(size_t)seli[k] * VALUE_DIM + tid];
    out[tid] = acc;
  }
}

// ---------------- launch ----------------

extern "C" void kernel_launch(void* const* d_in, const int* in_sizes, int n_in,
                              void* d_out, int out_size, void* d_ws, size_t ws_size,
                              hipStream_t stream) {
  const float* query  = (const float*)d_in[0];
  const float* W1     = (const float*)d_in[1];
  const float* b1     = (const float*)d_in[2];
  const float* W2     = (const float*)d_in[3];
  const float* b2     = (const float*)d_in[4];
  const float* ln_g   = (const float*)d_in[5];
  const float* ln_b   = (const float*)d_in[6];
  const float* keys   = (const float*)d_in[7];
  const float* values = (const float*)d_in[8];
  float* out = (float*)d_out;

  float* wsf = (float*)d_ws;
  float* h        = wsf;                               // 512
  float* g        = wsf + 512;                         // 512
  float* cand_val = wsf + 1024;                        // NCAND
  int*   cand_idx = (int*)(wsf + 1024 + NCAND);        // NCAND

  hipLaunchKernelGGL(matvec1_kernel, dim3(128), dim3(256), 0, stream, query, W1, b1, h);
  hipLaunchKernelGGL(matvec2_kernel, dim3(128), dim3(256), 0, stream, h, W2, b2, g);
  hipLaunchKernelGGL(scan_kernel, dim3(SCAN_BLOCKS), dim3(256), 0, stream,
                     keys, g, ln_g, ln_b, cand_val, cand_idx);
  hipLaunchKernelGGL(final_kernel, dim3(1), dim3(1024), 0, stream,
                     cand_val, cand_idx, NCAND, values, out);
}

// Round 10
// 299.737 us; speedup vs baseline: 1.1780x; 1.0528x over previous
//
#include <hip/hip_runtime.h>
#include <math.h>

#define KEY_DIM   512
#define VALUE_DIM 128
#define CAP       500000
#define NRET      32
#define LN_EPS    1e-5f
#define NORM_EPS  1e-12f
#define NEG_INF   (-3.402823466e38f)
#define IDX_INF   0x7fffffff

#define SCAN_BLOCKS 489              // ceil(500000 / 1024); wave = 256 rows, block = 1024 rows
#define NCAND       (SCAN_BLOCKS * NRET)   // 15648
#define FIN_SLOTS   16               // 16*1024 = 16384 >= 15648

// ---------------- cross-lane primitives ----------------

template<int CTRL>
__device__ inline float dppMovF(float x) {
  return __int_as_float(__builtin_amdgcn_update_dpp(0, __float_as_int(x), CTRL, 0xF, 0xF, true));
}

// full 64-lane sum, result in every lane
__device__ inline float waveSumF(float x) {
  x += dppMovF<0xB1>(x);    // quad_perm xor1
  x += dppMovF<0x4E>(x);    // quad_perm xor2
  x += dppMovF<0x124>(x);   // row_ror:4
  x += dppMovF<0x128>(x);   // row_ror:8  -> row-of-16 sum
  x += __int_as_float(__builtin_amdgcn_ds_swizzle(__float_as_int(x), 0x401F)); // xor16
  x += __shfl_xor(x, 32);                                                      // xor32
  return x;
}

template<int D>
__device__ inline int fetchI(int x) {
  if constexpr (D == 1)       return __builtin_amdgcn_update_dpp(0, x, 0xB1, 0xF, 0xF, true);
  else if constexpr (D == 2)  return __builtin_amdgcn_update_dpp(0, x, 0x4E, 0xF, 0xF, true);
  else if constexpr (D == 4)  return __builtin_amdgcn_ds_swizzle(x, 0x101F);  // xor4
  else if constexpr (D == 8)  return __builtin_amdgcn_ds_swizzle(x, 0x201F);  // xor8
  else if constexpr (D == 16) return __builtin_amdgcn_ds_swizzle(x, 0x401F);  // xor16
  else                        return __shfl_xor(x, 32);                       // xor32
}
template<int D>
__device__ inline float fetchF(float x) { return __int_as_float(fetchI<D>(__float_as_int(x))); }

// one butterfly step of argmax by (v desc, gi asc) carrying payload code
template<int D>
__device__ inline void amStep(float& v, int& g, int& c) {
  float ov = fetchF<D>(v); int og = fetchI<D>(g); int oc = fetchI<D>(c);
  if (ov > v || (ov == v && og < g)) { v = ov; g = og; c = oc; }
}
__device__ inline void waveArgMax3(float& v, int& g, int& c) {
  amStep<1>(v, g, c); amStep<2>(v, g, c); amStep<4>(v, g, c);
  amStep<8>(v, g, c); amStep<16>(v, g, c); amStep<32>(v, g, c);
}

// bitonic compare-exchange, partner at lane^D (same register)
template<int D>
__device__ inline void ceStageLane(float& v, int& gi, bool desc, int lane) {
  float ov = fetchF<D>(v); int og = fetchI<D>(gi);
  bool better  = (ov > v) || (ov == v && og < gi);
  bool amLower = (lane & D) == 0;
  bool keepMax = (amLower == desc);
  if (keepMax == better) { v = ov; gi = og; }
}

// bitonic compare-exchange between two registers (A holds the lower element id)
__device__ inline void ceStageReg(float& vA, int& gA, float& vB, int& gB, bool desc) {
  bool better = (vB > vA) || (vB == vA && gB < gA);
  bool sw = (better == desc);
  float tv = sw ? vB : vA; vB = sw ? vA : vB; vA = tv;
  int   tg = sw ? gB : gA; gB = sw ? gA : gB; gA = tg;
}

// ---------------- MLP matvecs ----------------

__global__ __launch_bounds__(256) void matvec1_kernel(
    const float* __restrict__ query, const float* __restrict__ W1,
    const float* __restrict__ b1, float* __restrict__ h)
{
  int tid = threadIdx.x, wid = tid >> 6, lane = tid & 63;
  int row = (blockIdx.x << 2) + wid;
  const float4* q4 = (const float4*)query;
  const float4* wrow = (const float4*)(W1 + (size_t)row * KEY_DIM);
  float4 a0 = wrow[lane],      q0 = q4[lane];
  float4 a1 = wrow[lane + 64], q1 = q4[lane + 64];
  float acc = a0.x*q0.x + a0.y*q0.y + a0.z*q0.z + a0.w*q0.w
            + a1.x*q1.x + a1.y*q1.y + a1.z*q1.z + a1.w*q1.w;
  acc = waveSumF(acc);
  if (lane == 0) {
    float x = acc + b1[row];
    h[row] = x / (1.f + expf(-x));   // silu
  }
}

__global__ __launch_bounds__(256) void matvec2_kernel(
    const float* __restrict__ h, const float* __restrict__ W2,
    const float* __restrict__ b2, float* __restrict__ g)
{
  int tid = threadIdx.x, wid = tid >> 6, lane = tid & 63;
  int row = (blockIdx.x << 2) + wid;
  const float4* h4 = (const float4*)h;
  const float4* wrow = (const float4*)(W2 + (size_t)row * KEY_DIM);
  float4 a0 = wrow[lane],      q0 = h4[lane];
  float4 a1 = wrow[lane + 64], q1 = h4[lane + 64];
  float acc = a0.x*q0.x + a0.y*q0.y + a0.z*q0.z + a0.w*q0.w
            + a1.x*q1.x + a1.y*q1.y + a1.z*q1.z + a1.w*q1.w;
  acc = waveSumF(acc);
  if (lane == 0) g[row] = acc + b2[row];
}

// ---------------- scan: inline LN/L2 + batch-8 VGPR loads + sort-256 + block merge ----------------
// 489 blocks x 256 (4 waves); wave owns 256 consecutive rows (4 segs x 8 batches x 8 rows).
// This is the best-measured passing scan structure (278.9 us total) + block-level merge.

__global__ __launch_bounds__(256, 4) void scan_kernel(
    const float* __restrict__ keys, const float* __restrict__ g,
    const float* __restrict__ ln_g, const float* __restrict__ ln_b,
    float* __restrict__ cand_val, int* __restrict__ cand_idx)
{
  __shared__ float lv[128];
  __shared__ int   li[128];
  const int tid = threadIdx.x, wid = tid >> 6, lane = tid & 63;

  // ---- per-wave LayerNorm + L2-normalize of g[512] -> q0,q1 (lane layout matches keys reads) ----
  const float4* g4 = (const float4*)g;
  float4 x0 = g4[lane], x1 = g4[lane + 64];
  float psum = x0.x + x0.y + x0.z + x0.w + x1.x + x1.y + x1.z + x1.w;
  float mu = waveSumF(psum) * (1.f / 512.f);
  float4 d0, d1;
  d0.x = x0.x - mu; d0.y = x0.y - mu; d0.z = x0.z - mu; d0.w = x0.w - mu;
  d1.x = x1.x - mu; d1.y = x1.y - mu; d1.z = x1.z - mu; d1.w = x1.w - mu;
  float pvar = d0.x*d0.x + d0.y*d0.y + d0.z*d0.z + d0.w*d0.w
             + d1.x*d1.x + d1.y*d1.y + d1.z*d1.z + d1.w*d1.w;
  float var  = waveSumF(pvar) * (1.f / 512.f);
  float rstd = 1.f / sqrtf(var + LN_EPS);
  const float4* lg4 = (const float4*)ln_g;
  const float4* lb4 = (const float4*)ln_b;
  float4 a0 = lg4[lane], a1 = lg4[lane + 64];
  float4 b0 = lb4[lane], b1 = lb4[lane + 64];
  float4 y0, y1;
  y0.x = d0.x*rstd*a0.x + b0.x; y0.y = d0.y*rstd*a0.y + b0.y;
  y0.z = d0.z*rstd*a0.z + b0.z; y0.w = d0.w*rstd*a0.w + b0.w;
  y1.x = d1.x*rstd*a1.x + b1.x; y1.y = d1.y*rstd*a1.y + b1.y;
  y1.z = d1.z*rstd*a1.z + b1.z; y1.w = d1.w*rstd*a1.w + b1.w;
  float pn  = y0.x*y0.x + y0.y*y0.y + y0.z*y0.z + y0.w*y0.w
            + y1.x*y1.x + y1.y*y1.y + y1.z*y1.z + y1.w*y1.w;
  float nsq = waveSumF(pn);
  float nf  = 1.f / fmaxf(sqrtf(nsq), NORM_EPS);
  float4 q0, q1;
  q0.x = y0.x*nf; q0.y = y0.y*nf; q0.z = y0.z*nf; q0.w = y0.w*nf;
  q1.x = y1.x*nf; q1.y = y1.y*nf; q1.z = y1.z*nf; q1.w = y1.w*nf;

  // ---- scan 256 rows: 4 segments x 8 batches x 8 rows ----
  const char* kl = (const char*)keys + (size_t)lane * 16;   // lane's 16B column slice
  const int wrow0 = (blockIdx.x << 10) + (wid << 8);

  float sv[4]; int sg[4];

  #pragma unroll
  for (int seg = 0; seg < 4; ++seg) {
    const int segbase = wrow0 + (seg << 6);
    float simreg = NEG_INF;
    #pragma unroll 1
    for (int bi = 0; bi < 8; ++bi) {
      const int r0 = segbase + (bi << 3);
      float4 A[8], B[8];
      #pragma unroll
      for (int i = 0; i < 8; ++i) {
        int rr = min(r0 + i, CAP - 1);
        const char* rp = kl + (size_t)rr * 2048;
        A[i] = *(const float4*)rp;
        B[i] = *(const float4*)(rp + 1024);
      }
      float dt[8], sq[8];
      #pragma unroll
      for (int i = 0; i < 8; ++i) {
        dt[i] = A[i].x*q0.x + A[i].y*q0.y + A[i].z*q0.z + A[i].w*q0.w
              + B[i].x*q1.x + B[i].y*q1.y + B[i].z*q1.z + B[i].w*q1.w;
        sq[i] = A[i].x*A[i].x + A[i].y*A[i].y + A[i].z*A[i].z + A[i].w*A[i].w
              + B[i].x*B[i].x + B[i].y*B[i].y + B[i].z*B[i].z + B[i].w*B[i].w;
      }
      #pragma unroll
      for (int i = 0; i < 8; ++i) { dt[i] = waveSumF(dt[i]); sq[i] = waveSumF(sq[i]); }
      #pragma unroll
      for (int i = 0; i < 8; ++i) {
        float sim = dt[i] / fmaxf(sqrtf(sq[i]), NORM_EPS);
        bool ok = (r0 + i) < CAP;
        sim = ok ? sim : NEG_INF;
        int rb = (bi << 3) + i;               // 0..63 within segment
        simreg = (lane == rb) ? sim : simreg;
      }
    }
    sv[seg] = simreg;
    sg[seg] = segbase + lane;                 // row index (>= CAP only when v == NEG_INF)
  }

  // ---- bitonic sort of 256 (element id e = seg*64 + lane), descending by (v, gi asc) ----
  #define LST4(D, A0, A1, A2, A3) \
    ceStageLane<D>(sv[0], sg[0], A0, lane); \
    ceStageLane<D>(sv[1], sg[1], A1, lane); \
    ceStageLane<D>(sv[2], sg[2], A2, lane); \
    ceStageLane<D>(sv[3], sg[3], A3, lane);

  { bool dm = (lane & 2) == 0;  LST4(1, dm,dm,dm,dm) }                               // m=2
  { bool dm = (lane & 4) == 0;  LST4(2, dm,dm,dm,dm)  LST4(1, dm,dm,dm,dm) }         // m=4
  { bool dm = (lane & 8) == 0;  LST4(4, dm,dm,dm,dm)  LST4(2, dm,dm,dm,dm)
                                LST4(1, dm,dm,dm,dm) }                               // m=8
  { bool dm = (lane & 16) == 0; LST4(8, dm,dm,dm,dm)  LST4(4, dm,dm,dm,dm)
                                LST4(2, dm,dm,dm,dm)  LST4(1, dm,dm,dm,dm) }         // m=16
  { bool dm = (lane & 32) == 0; LST4(16, dm,dm,dm,dm) LST4(8, dm,dm,dm,dm)
                                LST4(4, dm,dm,dm,dm)  LST4(2, dm,dm,dm,dm)
                                LST4(1, dm,dm,dm,dm) }                               // m=32
  // m=64: desc per reg = ((e&64)==0) -> T,F,T,F
  LST4(32, true,false,true,false) LST4(16, true,false,true,false)
  LST4(8,  true,false,true,false) LST4(4,  true,false,true,false)
  LST4(2,  true,false,true,false) LST4(1,  true,false,true,false)
  // m=128: d=64 cross-reg pairs (0,1) desc=T, (2,3) desc=F; then lanes, desc T,T,F,F
  ceStageReg(sv[0], sg[0], sv[1], sg[1], true);
  ceStageReg(sv[2], sg[2], sv[3], sg[3], false);
  LST4(32, true,true,false,false) LST4(16, true,true,false,false)
  LST4(8,  true,true,false,false) LST4(4,  true,true,false,false)
  LST4(2,  true,true,false,false) LST4(1,  true,true,false,false)
  // m=256: d=128, then d=64, then lanes (all desc)
  ceStageReg(sv[0], sg[0], sv[2], sg[2], true);
  ceStageReg(sv[1], sg[1], sv[3], sg[3], true);
  ceStageReg(sv[0], sg[0], sv[1], sg[1], true);
  ceStageReg(sv[2], sg[2], sv[3], sg[3], true);
  LST4(32, true,true,true,true) LST4(16, true,true,true,true)
  LST4(8,  true,true,true,true) LST4(4,  true,true,true,true)
  LST4(2,  true,true,true,true) LST4(1,  true,true,true,true)
  #undef LST4

  // ---- block merge: 4 waves x top-32 -> block top-32 ----
  if (lane < NRET) { lv[(wid << 5) + lane] = sv[0]; li[(wid << 5) + lane] = sg[0]; }
  __syncthreads();
  if (wid == 0) {
    float c0 = lv[lane], c1 = lv[64 + lane];
    int   h0 = li[lane], h1 = li[64 + lane];
    for (int it = 0; it < NRET; ++it) {
      bool p1 = (c1 > c0) || (c1 == c0 && h1 < h0);
      float bv = p1 ? c1 : c0; int bg = p1 ? h1 : h0;
      int code = (lane << 1) | (p1 ? 1 : 0);
      waveArgMax3(bv, bg, code);
      if (lane == (code >> 1)) { if (code & 1) c1 = NEG_INF; else c0 = NEG_INF; }
      if (lane == 0) {
        cand_val[(blockIdx.x << 5) + it] = bv;
        cand_idx[(blockIdx.x << 5) + it] = bg;
      }
    }
  }
}

// ---------------- final: 15648 -> top-32, softmax, weighted gather ----------------
// 1 block x 1024 (16 waves); per-wave extraction, then wave 0 over 512, then output

__global__ __launch_bounds__(1024) void final_kernel(
    const float* __restrict__ cv, const int* __restrict__ ci, int n,
    const float* __restrict__ values, float* __restrict__ out)
{
  __shared__ float wv[512];
  __shared__ int   wgi[512];
  __shared__ float selv[NRET];
  __shared__ int   seli[NRET];
  __shared__ float attn[NRET];
  int tid = threadIdx.x, wid = tid >> 6, lane = tid & 63;

  float vs[FIN_SLOTS]; int gs[FIN_SLOTS];
  #pragma unroll
  for (int k = 0; k < FIN_SLOTS; ++k) {
    int idx = (k << 10) + tid;
    bool ok = idx < n;
    vs[k] = ok ? cv[idx] : NEG_INF;
    gs[k] = ok ? ci[idx] : IDX_INF;
  }
  // per-wave top-32 extraction
  for (int it = 0; it < NRET; ++it) {
    float bv = vs[0]; int bg = gs[0]; int bs = 0;
    #pragma unroll
    for (int k = 1; k < FIN_SLOTS; ++k)
      if (vs[k] > bv || (vs[k] == bv && gs[k] < bg)) { bv = vs[k]; bg = gs[k]; bs = k; }
    int code = (lane << 4) | bs;
    waveArgMax3(bv, bg, code);
    if (lane == (code >> 4)) {
      int s = code & 15;
      #pragma unroll
      for (int k = 0; k < FIN_SLOTS; ++k) if (k == s) vs[k] = NEG_INF;
    }
    if (lane == 0) { wv[(wid << 5) + it] = bv; wgi[(wid << 5) + it] = bg; }
  }
  __syncthreads();
  // wave 0: 512 -> 32 (8 slots/lane)
  if (wid == 0) {
    float fs[8]; int fg[8];
    #pragma unroll
    for (int k = 0; k < 8; ++k) { fs[k] = wv[(k << 6) + lane]; fg[k] = wgi[(k << 6) + lane]; }
    for (int it = 0; it < NRET; ++it) {
      float bv = fs[0]; int bg = fg[0]; int bs = 0;
      #pragma unroll
      for (int k = 1; k < 8; ++k)
        if (fs[k] > bv || (fs[k] == bv && fg[k] < bg)) { bv = fs[k]; bg = fg[k]; bs = k; }
      int code = (lane << 3) | bs;
      waveArgMax3(bv, bg, code);
      if (lane == (code >> 3)) {
        int s = code & 7;
        #pragma unroll
        for (int k = 0; k < 8; ++k) if (k == s) fs[k] = NEG_INF;
      }
      if (lane == 0) { selv[it] = bv; seli[it] = bg; }
    }
  }
  __syncthreads();
  if (tid < NRET) {
    float e = expf(selv[tid] - selv[0]);   // selv[0] is the max
    float s = e;
    #pragma unroll
    for (int off = 16; off; off >>= 1) s += __shfl_xor(s, off);
    attn[tid] = e / s;
  }
  __syncthreads();
  if (tid < VALUE_DIM) {
    float acc = 0.f;
    #pragma unroll
    for (int k = 0; k < NRET; ++k)
      acc += attn[k] * values[(size_t)seli[k] * VALUE_DIM + tid];
    out[tid] = acc;
  }
}

// ---------------- launch ----------------

extern "C" void kernel_launch(void* const* d_in, const int* in_sizes, int n_in,
                              void* d_out, int out_size, void* d_ws, size_t ws_size,
                              hipStream_t stream) {
  const float* query  = (const float*)d_in[0];
  const float* W1     = (const float*)d_in[1];
  const float* b1     = (const float*)d_in[2];
  const float* W2     = (const float*)d_in[3];
  const float* b2     = (const float*)d_in[4];
  const float* ln_g   = (const float*)d_in[5];
  const float* ln_b   = (const float*)d_in[6];
  const float* keys   = (const float*)d_in[7];
  const float* values = (const float*)d_in[8];
  float* out = (float*)d_out;

  float* wsf = (float*)d_ws;
  float* h        = wsf;                               // 512
  float* g        = wsf + 512;                         // 512
  float* cand_val = wsf + 1024;                        // NCAND
  int*   cand_idx = (int*)(wsf + 1024 + NCAND);        // NCAND

  hipLaunchKernelGGL(matvec1_kernel, dim3(128), dim3(256), 0, stream, query, W1, b1, h);
  hipLaunchKernelGGL(matvec2_kernel, dim3(128), dim3(256), 0, stream, h, W2, b2, g);
  hipLaunchKernelGGL(scan_kernel, dim3(SCAN_BLOCKS), dim3(256), 0, stream,
                     keys, g, ln_g, ln_b, cand_val, cand_idx);
  hipLaunchKernelGGL(final_kernel, dim3(1), dim3(1024), 0, stream,
                     cand_val, cand_idx, NCAND, values, out);
}

// Round 11
// 278.666 us; speedup vs baseline: 1.2670x; 1.0756x over previous
//
#include <hip/hip_runtime.h>
#include <math.h>

#define KEY_DIM   512
#define VALUE_DIM 128
#define CAP       500000
#define NRET      32
#define LN_EPS    1e-5f
#define NORM_EPS  1e-12f
#define NEG_INF   (-3.402823466e38f)
#define IDX_INF   0x7fffffff

#define SCAN_BLOCKS 489              // ceil(500000 / 1024); wave = 256 rows, block = 1024 rows
#define NCAND       (SCAN_BLOCKS * 4 * 32)   // 62592
#define M1_BLOCKS   62               // ceil(NCAND / 1024)
#define N2          (M1_BLOCKS * 32) // 1984

// ---------------- cross-lane primitives ----------------

template<int CTRL>
__device__ inline float dppMovF(float x) {
  return __int_as_float(__builtin_amdgcn_update_dpp(0, __float_as_int(x), CTRL, 0xF, 0xF, true));
}

// full 64-lane sum, result in every lane
__device__ inline float waveSumF(float x) {
  x += dppMovF<0xB1>(x);    // quad_perm xor1
  x += dppMovF<0x4E>(x);    // quad_perm xor2
  x += dppMovF<0x124>(x);   // row_ror:4
  x += dppMovF<0x128>(x);   // row_ror:8  -> row-of-16 sum
  x += __int_as_float(__builtin_amdgcn_ds_swizzle(__float_as_int(x), 0x401F)); // xor16
  x += __shfl_xor(x, 32);                                                      // xor32
  return x;
}

template<int D>
__device__ inline int fetchI(int x) {
  if constexpr (D == 1)       return __builtin_amdgcn_update_dpp(0, x, 0xB1, 0xF, 0xF, true);
  else if constexpr (D == 2)  return __builtin_amdgcn_update_dpp(0, x, 0x4E, 0xF, 0xF, true);
  else if constexpr (D == 4)  return __builtin_amdgcn_ds_swizzle(x, 0x101F);  // xor4
  else if constexpr (D == 8)  return __builtin_amdgcn_ds_swizzle(x, 0x201F);  // xor8
  else if constexpr (D == 16) return __builtin_amdgcn_ds_swizzle(x, 0x401F);  // xor16
  else                        return __shfl_xor(x, 32);                       // xor32
}
template<int D>
__device__ inline float fetchF(float x) { return __int_as_float(fetchI<D>(__float_as_int(x))); }

// one butterfly step of argmax by (v desc, gi asc) carrying payload code
template<int D>
__device__ inline void amStep(float& v, int& g, int& c) {
  float ov = fetchF<D>(v); int og = fetchI<D>(g); int oc = fetchI<D>(c);
  if (ov > v || (ov == v && og < g)) { v = ov; g = og; c = oc; }
}
__device__ inline void waveArgMax3(float& v, int& g, int& c) {
  amStep<1>(v, g, c); amStep<2>(v, g, c); amStep<4>(v, g, c);
  amStep<8>(v, g, c); amStep<16>(v, g, c); amStep<32>(v, g, c);
}

// bitonic compare-exchange, partner at lane^D (same register)
template<int D>
__device__ inline void ceStageLane(float& v, int& gi, bool desc, int lane) {
  float ov = fetchF<D>(v); int og = fetchI<D>(gi);
  bool better  = (ov > v) || (ov == v && og < gi);
  bool amLower = (lane & D) == 0;
  bool keepMax = (amLower == desc);
  if (keepMax == better) { v = ov; gi = og; }
}

// bitonic compare-exchange between two registers (A holds the lower element id)
__device__ inline void ceStageReg(float& vA, int& gA, float& vB, int& gB, bool desc) {
  bool better = (vB > vA) || (vB == vA && gB < gA);
  bool sw = (better == desc);
  float tv = sw ? vB : vA; vB = sw ? vA : vB; vA = tv;
  int   tg = sw ? gB : gA; gB = sw ? gA : gB; gA = tg;
}

// ---------------- MLP matvecs ----------------

__global__ __launch_bounds__(256) void matvec1_kernel(
    const float* __restrict__ query, const float* __restrict__ W1,
    const float* __restrict__ b1, float* __restrict__ h)
{
  int tid = threadIdx.x, wid = tid >> 6, lane = tid & 63;
  int row = (blockIdx.x << 2) + wid;
  const float4* q4 = (const float4*)query;
  const float4* wrow = (const float4*)(W1 + (size_t)row * KEY_DIM);
  float4 a0 = wrow[lane],      q0 = q4[lane];
  float4 a1 = wrow[lane + 64], q1 = q4[lane + 64];
  float acc = a0.x*q0.x + a0.y*q0.y + a0.z*q0.z + a0.w*q0.w
            + a1.x*q1.x + a1.y*q1.y + a1.z*q1.z + a1.w*q1.w;
  acc = waveSumF(acc);
  if (lane == 0) {
    float x = acc + b1[row];
    h[row] = x / (1.f + expf(-x));   // silu
  }
}

__global__ __launch_bounds__(256) void matvec2_kernel(
    const float* __restrict__ h, const float* __restrict__ W2,
    const float* __restrict__ b2, float* __restrict__ g)
{
  int tid = threadIdx.x, wid = tid >> 6, lane = tid & 63;
  int row = (blockIdx.x << 2) + wid;
  const float4* h4 = (const float4*)h;
  const float4* wrow = (const float4*)(W2 + (size_t)row * KEY_DIM);
  float4 a0 = wrow[lane],      q0 = h4[lane];
  float4 a1 = wrow[lane + 64], q1 = h4[lane + 64];
  float acc = a0.x*q0.x + a0.y*q0.y + a0.z*q0.z + a0.w*q0.w
            + a1.x*q1.x + a1.y*q1.y + a1.z*q1.z + a1.w*q1.w;
  acc = waveSumF(acc);
  if (lane == 0) g[row] = acc + b2[row];
}

// ---------------- scan: inline LN/L2 + cosine sims + per-wave sort-256 top-32 ----------------
// 489 blocks x 256; wave owns 256 consecutive rows; batches of 8 rows (16 loads in flight)

__global__ __launch_bounds__(256, 4) void scan_kernel(
    const float* __restrict__ keys, const float* __restrict__ g,
    const float* __restrict__ ln_g, const float* __restrict__ ln_b,
    float* __restrict__ cand_val, int* __restrict__ cand_idx)
{
  const int tid = threadIdx.x, wid = tid >> 6, lane = tid & 63;

  // ---- per-wave LayerNorm + L2-normalize of g[512] -> q0,q1 (lane layout matches keys reads) ----
  const float4* g4 = (const float4*)g;
  float4 x0 = g4[lane], x1 = g4[lane + 64];
  float psum = x0.x + x0.y + x0.z + x0.w + x1.x + x1.y + x1.z + x1.w;
  float mu = waveSumF(psum) * (1.f / 512.f);
  float4 d0, d1;
  d0.x = x0.x - mu; d0.y = x0.y - mu; d0.z = x0.z - mu; d0.w = x0.w - mu;
  d1.x = x1.x - mu; d1.y = x1.y - mu; d1.z = x1.z - mu; d1.w = x1.w - mu;
  float pvar = d0.x*d0.x + d0.y*d0.y + d0.z*d0.z + d0.w*d0.w
             + d1.x*d1.x + d1.y*d1.y + d1.z*d1.z + d1.w*d1.w;
  float var  = waveSumF(pvar) * (1.f / 512.f);
  float rstd = 1.f / sqrtf(var + LN_EPS);
  const float4* lg4 = (const float4*)ln_g;
  const float4* lb4 = (const float4*)ln_b;
  float4 a0 = lg4[lane], a1 = lg4[lane + 64];
  float4 b0 = lb4[lane], b1 = lb4[lane + 64];
  float4 y0, y1;
  y0.x = d0.x*rstd*a0.x + b0.x; y0.y = d0.y*rstd*a0.y + b0.y;
  y0.z = d0.z*rstd*a0.z + b0.z; y0.w = d0.w*rstd*a0.w + b0.w;
  y1.x = d1.x*rstd*a1.x + b1.x; y1.y = d1.y*rstd*a1.y + b1.y;
  y1.z = d1.z*rstd*a1.z + b1.z; y1.w = d1.w*rstd*a1.w + b1.w;
  float pn  = y0.x*y0.x + y0.y*y0.y + y0.z*y0.z + y0.w*y0.w
            + y1.x*y1.x + y1.y*y1.y + y1.z*y1.z + y1.w*y1.w;
  float nsq = waveSumF(pn);
  float nf  = 1.f / fmaxf(sqrtf(nsq), NORM_EPS);
  float4 q0, q1;
  q0.x = y0.x*nf; q0.y = y0.y*nf; q0.z = y0.z*nf; q0.w = y0.w*nf;
  q1.x = y1.x*nf; q1.y = y1.y*nf; q1.z = y1.z*nf; q1.w = y1.w*nf;

  // ---- scan 256 rows: 4 segments x 8 batches x 8 rows ----
  const char* kl = (const char*)keys + (size_t)lane * 16;   // lane's 16B column slice
  const int wrow0 = (blockIdx.x << 10) + (wid << 8);

  float sv[4]; int sg[4];

  #pragma unroll
  for (int seg = 0; seg < 4; ++seg) {
    const int segbase = wrow0 + (seg << 6);
    float simreg = NEG_INF;
    #pragma unroll 1
    for (int bi = 0; bi < 8; ++bi) {
      const int r0 = segbase + (bi << 3);
      float4 A[8], B[8];
      #pragma unroll
      for (int i = 0; i < 8; ++i) {
        int rr = min(r0 + i, CAP - 1);
        const char* rp = kl + (size_t)rr * 2048;
        A[i] = *(const float4*)rp;
        B[i] = *(const float4*)(rp + 1024);
      }
      float dt[8], sq[8];
      #pragma unroll
      for (int i = 0; i < 8; ++i) {
        dt[i] = A[i].x*q0.x + A[i].y*q0.y + A[i].z*q0.z + A[i].w*q0.w
              + B[i].x*q1.x + B[i].y*q1.y + B[i].z*q1.z + B[i].w*q1.w;
        sq[i] = A[i].x*A[i].x + A[i].y*A[i].y + A[i].z*A[i].z + A[i].w*A[i].w
              + B[i].x*B[i].x + B[i].y*B[i].y + B[i].z*B[i].z + B[i].w*B[i].w;
      }
      #pragma unroll
      for (int i = 0; i < 8; ++i) { dt[i] = waveSumF(dt[i]); sq[i] = waveSumF(sq[i]); }
      #pragma unroll
      for (int i = 0; i < 8; ++i) {
        float sim = dt[i] / fmaxf(sqrtf(sq[i]), NORM_EPS);
        bool ok = (r0 + i) < CAP;
        sim = ok ? sim : NEG_INF;
        int rb = (bi << 3) + i;               // 0..63 within segment
        simreg = (lane == rb) ? sim : simreg;
      }
    }
    sv[seg] = simreg;
    sg[seg] = segbase + lane;                 // row index (may be >= CAP only when v == NEG_INF)
  }

  // ---- bitonic sort of 256 (element id e = seg*64 + lane), descending by (v, gi asc) ----
  #define LST4(D, A0, A1, A2, A3) \
    ceStageLane<D>(sv[0], sg[0], A0, lane); \
    ceStageLane<D>(sv[1], sg[1], A1, lane); \
    ceStageLane<D>(sv[2], sg[2], A2, lane); \
    ceStageLane<D>(sv[3], sg[3], A3, lane);

  { bool dm = (lane & 2) == 0;  LST4(1, dm,dm,dm,dm) }                               // m=2
  { bool dm = (lane & 4) == 0;  LST4(2, dm,dm,dm,dm)  LST4(1, dm,dm,dm,dm) }         // m=4
  { bool dm = (lane & 8) == 0;  LST4(4, dm,dm,dm,dm)  LST4(2, dm,dm,dm,dm)
                                LST4(1, dm,dm,dm,dm) }                               // m=8
  { bool dm = (lane & 16) == 0; LST4(8, dm,dm,dm,dm)  LST4(4, dm,dm,dm,dm)
                                LST4(2, dm,dm,dm,dm)  LST4(1, dm,dm,dm,dm) }         // m=16
  { bool dm = (lane & 32) == 0; LST4(16, dm,dm,dm,dm) LST4(8, dm,dm,dm,dm)
                                LST4(4, dm,dm,dm,dm)  LST4(2, dm,dm,dm,dm)
                                LST4(1, dm,dm,dm,dm) }                               // m=32
  // m=64: desc per reg = ((e&64)==0) -> T,F,T,F
  LST4(32, true,false,true,false) LST4(16, true,false,true,false)
  LST4(8,  true,false,true,false) LST4(4,  true,false,true,false)
  LST4(2,  true,false,true,false) LST4(1,  true,false,true,false)
  // m=128: d=64 cross-reg pairs (0,1) desc=T, (2,3) desc=F; then lanes, desc T,T,F,F
  ceStageReg(sv[0], sg[0], sv[1], sg[1], true);
  ceStageReg(sv[2], sg[2], sv[3], sg[3], false);
  LST4(32, true,true,false,false) LST4(16, true,true,false,false)
  LST4(8,  true,true,false,false) LST4(4,  true,true,false,false)
  LST4(2,  true,true,false,false) LST4(1,  true,true,false,false)
  // m=256: d=128, then d=64, then lanes (all desc)
  ceStageReg(sv[0], sg[0], sv[2], sg[2], true);
  ceStageReg(sv[1], sg[1], sv[3], sg[3], true);
  ceStageReg(sv[0], sg[0], sv[1], sg[1], true);
  ceStageReg(sv[2], sg[2], sv[3], sg[3], true);
  LST4(32, true,true,true,true) LST4(16, true,true,true,true)
  LST4(8,  true,true,true,true) LST4(4,  true,true,true,true)
  LST4(2,  true,true,true,true) LST4(1,  true,true,true,true)
  #undef LST4

  // top-32 of this wave = reg0, lanes 0..31
  if (lane < NRET) {
    int w = (blockIdx.x << 2) + wid;
    cand_val[w * NRET + lane] = sv[0];
    cand_idx[w * NRET + lane] = sg[0];
  }
}

// ---------------- merge: 1024 candidates/block -> block top-32 ----------------

__global__ __launch_bounds__(256) void merge_kernel(
    const float* __restrict__ in_val, const int* __restrict__ in_idx, int n,
    float* __restrict__ out_val, int* __restrict__ out_idx)
{
  __shared__ float lv[128];
  __shared__ int   li[128];
  int tid = threadIdx.x, wid = tid >> 6, lane = tid & 63;

  float vs[4]; int gs[4];
  int base = (blockIdx.x << 10) + (wid << 8);
  #pragma unroll
  for (int k = 0; k < 4; ++k) {
    int idx = base + (k << 6) + lane;
    bool ok = idx < n;
    vs[k] = ok ? in_val[idx] : NEG_INF;
    gs[k] = ok ? in_idx[idx] : IDX_INF;
  }
  // per-wave top-32 (4-slot tournament)
  for (int it = 0; it < NRET; ++it) {
    float bv = vs[0]; int bg = gs[0]; int bs = 0;
    #pragma unroll
    for (int k = 1; k < 4; ++k)
      if (vs[k] > bv || (vs[k] == bv && gs[k] < bg)) { bv = vs[k]; bg = gs[k]; bs = k; }
    int code = (lane << 2) | bs;
    waveArgMax3(bv, bg, code);
    if (lane == (code >> 2)) {
      int s = code & 3;
      if (s == 0) vs[0] = NEG_INF; else if (s == 1) vs[1] = NEG_INF;
      else if (s == 2) vs[2] = NEG_INF; else vs[3] = NEG_INF;
    }
    if (lane == 0) { lv[(wid << 5) + it] = bv; li[(wid << 5) + it] = bg; }
  }
  __syncthreads();
  // wave0: 128 -> 32
  if (wid == 0) {
    float c0 = lv[lane], c1 = lv[64 + lane];
    int   h0 = li[lane], h1 = li[64 + lane];
    for (int it = 0; it < NRET; ++it) {
      bool p1 = (c1 > c0) || (c1 == c0 && h1 < h0);
      float bv = p1 ? c1 : c0; int bg = p1 ? h1 : h0;
      int code = (lane << 1) | (p1 ? 1 : 0);
      waveArgMax3(bv, bg, code);
      if (lane == (code >> 1)) { if (code & 1) c1 = NEG_INF; else c0 = NEG_INF; }
      if (lane == 0) {
        out_val[(blockIdx.x << 5) + it] = bv;
        out_idx[(blockIdx.x << 5) + it] = bg;
      }
    }
  }
}

// ---------------- final: N2 -> top-32, softmax, weighted gather ----------------

__global__ __launch_bounds__(256) void final_kernel(
    const float* __restrict__ c2v, const int* __restrict__ c2i, int n,
    const float* __restrict__ values, float* __restrict__ out)
{
  __shared__ float lv[128];
  __shared__ int   li[128];
  __shared__ float selv[NRET];
  __shared__ int   seli[NRET];
  __shared__ float attn[NRET];
  int tid = threadIdx.x, wid = tid >> 6, lane = tid & 63;

  float vs[8]; int gs[8];
  int base = (wid << 9);
  #pragma unroll
  for (int k = 0; k < 8; ++k) {
    int idx = base + (k << 6) + lane;
    bool ok = idx < n;
    vs[k] = ok ? c2v[idx] : NEG_INF;
    gs[k] = ok ? c2i[idx] : IDX_INF;
  }
  for (int it = 0; it < NRET; ++it) {
    float bv = vs[0]; int bg = gs[0]; int bs = 0;
    #pragma unroll
    for (int k = 1; k < 8; ++k)
      if (vs[k] > bv || (vs[k] == bv && gs[k] < bg)) { bv = vs[k]; bg = gs[k]; bs = k; }
    int code = (lane << 3) | bs;
    waveArgMax3(bv, bg, code);
    if (lane == (code >> 3)) {
      int s = code & 7;
      #pragma unroll
      for (int k = 0; k < 8; ++k) if (k == s) vs[k] = NEG_INF;
    }
    if (lane == 0) { lv[(wid << 5) + it] = bv; li[(wid << 5) + it] = bg; }
  }
  __syncthreads();
  if (wid == 0) {
    float c0 = lv[lane], c1 = lv[64 + lane];
    int   h0 = li[lane], h1 = li[64 + lane];
    for (int it = 0; it < NRET; ++it) {
      bool p1 = (c1 > c0) || (c1 == c0 && h1 < h0);
      float bv = p1 ? c1 : c0; int bg = p1 ? h1 : h0;
      int code = (lane << 1) | (p1 ? 1 : 0);
      waveArgMax3(bv, bg, code);
      if (lane == (code >> 1)) { if (code & 1) c1 = NEG_INF; else c0 = NEG_INF; }
      if (lane == 0) { selv[it] = bv; seli[it] = bg; }
    }
  }
  __syncthreads();
  if (tid < NRET) {
    float e = expf(selv[tid] - selv[0]);   // selv[0] is the max
    float s = e;
    #pragma unroll
    for (int off = 16; off; off >>= 1) s += __shfl_xor(s, off);
    attn[tid] = e / s;
  }
  __syncthreads();
  if (tid < VALUE_DIM) {
    float acc = 0.f;
    #pragma unroll
    for (int k = 0; k < NRET; ++k)
      acc += attn[k] * values[(size_t)seli[k] * VALUE_DIM + tid];
    out[tid] = acc;
  }
}

// ---------------- launch ----------------

extern "C" void kernel_launch(void* const* d_in, const int* in_sizes, int n_in,
                              void* d_out, int out_size, void* d_ws, size_t ws_size,
                              hipStream_t stream) {
  const float* query  = (const float*)d_in[0];
  const float* W1     = (const float*)d_in[1];
  const float* b1     = (const float*)d_in[2];
  const float* W2     = (const float*)d_in[3];
  const float* b2     = (const float*)d_in[4];
  const float* ln_g   = (const float*)d_in[5];
  const float* ln_b   = (const float*)d_in[6];
  const float* keys   = (const float*)d_in[7];
  const float* values = (const float*)d_in[8];
  float* out = (float*)d_out;

  float* wsf = (float*)d_ws;
  float* h        = wsf;                               // 512
  float* g        = wsf + 512;                         // 512
  float* cand_val = wsf + 1024;                        // NCAND
  int*   cand_idx = (int*)(wsf + 1024 + NCAND);        // NCAND
  float* c2v      = wsf + 1024 + 2 * NCAND;            // N2
  int*   c2i      = (int*)(wsf + 1024 + 2 * NCAND + N2); // N2

  hipLaunchKernelGGL(matvec1_kernel, dim3(128), dim3(256), 0, stream, query, W1, b1, h);
  hipLaunchKernelGGL(matvec2_kernel, dim3(128), dim3(256), 0, stream, h, W2, b2, g);
  hipLaunchKernelGGL(scan_kernel, dim3(SCAN_BLOCKS), dim3(256), 0, stream,
                     keys, g, ln_g, ln_b, cand_val, cand_idx);
  hipLaunchKernelGGL(merge_kernel, dim3(M1_BLOCKS), dim3(256), 0, stream,
                     cand_val, cand_idx, NCAND, c2v, c2i);
  hipLaunchKernelGGL(final_kernel, dim3(1), dim3(256), 0, stream,
                     c2v, c2i, N2, values, out);
}